// Round 15
// baseline (359.269 us; speedup 1.0000x reference)
//
#include <hip/hip_runtime.h>
#include <hip/hip_bf16.h>

// MoEProcessor: B=4,S=2048 -> T=8192 tokens, D=1024, E=8, K=2. fp32 in/out.
// Round 22. R21 post-mortem: BK=128 regressed (73us, occ 16%) — drain is
// throughput-bound; 2-barrier convoy GEMM plateaued at 54-73us across 5
// variants; best = R13-exact (34304B LDS, LDS scalars, BK=64, 55.8us).
// This round: (1) GEMM reverted byte-exact to R13 best; (2) build_lists
// KILLED — routing lane0 atomicAdd-appends each token to its (slot,expert)
// list directly (order-free; 16K spread atomics ~0us). counts zeroed via
// hipMemsetAsync (graph-capturable). -1 launch, -1 serial kernel, -e01/w01.

typedef unsigned short u16;
typedef __bf16 bf16x8 __attribute__((ext_vector_type(8)));
typedef float floatx4 __attribute__((ext_vector_type(4)));
typedef unsigned short u16x8 __attribute__((ext_vector_type(8)));
typedef unsigned short u16x4 __attribute__((ext_vector_type(4)));

#define NTOK 8192
#define DDIM 1024
#define NEXP 8

__device__ __forceinline__ u16 f2bf(float f) {
    union { float f; unsigned int i; } c; c.f = f;
    unsigned int i = c.i;
    return (u16)((i + 0x7fffu + ((i >> 16) & 1u)) >> 16);
}

// async 16B-per-lane global->LDS copy. LDS dest is wave-uniform base + lane*16.
__device__ __forceinline__ void gl2l16(const u16* g, u16* l) {
    __builtin_amdgcn_global_load_lds(
        (const __attribute__((address_space(1))) unsigned int*)g,
        (__attribute__((address_space(3))) unsigned int*)l, 16, 0, 0);
}

// ---- fused aux: blocks 0..2047 = routing (+direct list append);
//                 blocks 2048..4095 = W transpose ----
__global__ __launch_bounds__(256) void routing_and_transpose(
    const float* __restrict__ x, const float* __restrict__ noise,
    const float* __restrict__ Wr, const float* __restrict__ br,
    const float* __restrict__ gamma, const float* __restrict__ beta,
    const float* __restrict__ W,
    int* __restrict__ counts, int* __restrict__ list_tok,
    float* __restrict__ list_w,
    u16* __restrict__ xb, u16* __restrict__ WT, int wxb) {
    __shared__ __align__(16) float smem[NEXP * DDIM]; // 32 KiB union
    const int t = threadIdx.x;

    if (blockIdx.x < 2048) {
        // ---------------- routing role ----------------
        float (*wrT)[DDIM] = (float(*)[DDIM])smem;     // [8][1024]
#pragma unroll
        for (int i = 0; i < 8; ++i) {
            int f4 = i * 256 + t;
            int d = f4 >> 1, half = (f4 & 1) * 4;
            float4 v = *(const float4*)&Wr[d * 8 + half];
            wrT[half + 0][d] = v.x; wrT[half + 1][d] = v.y;
            wrT[half + 2][d] = v.z; wrT[half + 3][d] = v.w;
        }
        __syncthreads();

        const int wave = t >> 6, lane = t & 63;
        const int tok = blockIdx.x * 4 + wave;
        const float4* xrow = (const float4*)(x + (size_t)tok * DDIM);
        u16* xbrow = xb + (size_t)tok * DDIM;
        float acc[8];
#pragma unroll
        for (int e = 0; e < 8; ++e) acc[e] = 0.f;
#pragma unroll
        for (int i = 0; i < 4; ++i) {
            int d4 = i * 64 + lane;
            float4 xv = xrow[d4];
            if (wxb) {
                u16x4 b;
                b[0] = f2bf(xv.x); b[1] = f2bf(xv.y);
                b[2] = f2bf(xv.z); b[3] = f2bf(xv.w);
                *(u16x4*)(xbrow + d4 * 4) = b;
            }
#pragma unroll
            for (int e = 0; e < 8; ++e) {
                float4 wv = *(const float4*)&wrT[e][d4 * 4];
                acc[e] += xv.x * wv.x + xv.y * wv.y + xv.z * wv.z + xv.w * wv.w;
            }
        }
#pragma unroll
        for (int off = 32; off >= 1; off >>= 1) {
#pragma unroll
            for (int e = 0; e < 8; ++e) acc[e] += __shfl_xor(acc[e], off, 64);
        }
        if (lane == 0) {
            float lg[8], mu = 0.f;
#pragma unroll
            for (int e = 0; e < 8; ++e) { lg[e] = acc[e] + br[e]; mu += lg[e]; }
            mu *= 0.125f;
            float var = 0.f;
#pragma unroll
            for (int e = 0; e < 8; ++e) { float d = lg[e] - mu; var += d * d; }
            var *= 0.125f;
            float rstd = rsqrtf(var + 1e-5f);
            float ln[8], mx = -1e30f;
#pragma unroll
            for (int e = 0; e < 8; ++e) {
                ln[e] = (lg[e] - mu) * rstd * gamma[e] + beta[e];
                mx = fmaxf(mx, ln[e]);
            }
            float s = 0.f, p[8];
#pragma unroll
            for (int e = 0; e < 8; ++e) { p[e] = expf(ln[e] - mx); s += p[e]; }
            float inv = 1.f / s, r[8];
#pragma unroll
            for (int e = 0; e < 8; ++e)
                r[e] = p[e] * inv + noise[(size_t)tok * 8 + e];
            int i0 = 0; float v0 = r[0];
#pragma unroll
            for (int e = 1; e < 8; ++e) if (r[e] > v0) { v0 = r[e]; i0 = e; }
            int i1 = -1; float v1 = -1e30f;
#pragma unroll
            for (int e = 0; e < 8; ++e)
                if (e != i0 && r[e] > v1) { v1 = r[e]; i1 = e; }
            float w0 = 1.f / (1.f + expf(v1 - v0));
            // direct list append (order-free): slot0 -> grp i0, slot1 -> grp 8+i1
            int p0 = atomicAdd(&counts[i0], 1);
            list_tok[i0 * NTOK + p0] = tok;
            list_w[i0 * NTOK + p0] = w0;
            int p1 = atomicAdd(&counts[8 + i1], 1);
            list_tok[(8 + i1) * NTOK + p1] = tok;
            list_w[(8 + i1) * NTOK + p1] = 1.f - w0;
        }
    } else {
        // ---------------- transpose role ----------------
        float* tileT = smem;                           // 64*65 floats used
        const int id2 = blockIdx.x - 2048;             // 0..2047
        const int e = id2 >> 8, d0 = ((id2 >> 4) & 15) * 64, f0 = (id2 & 15) * 64;
        const float* src = W + (size_t)e * DDIM * DDIM;
        u16* dst = WT + (size_t)e * DDIM * DDIM;
        const int r = t >> 2, q = t & 3;
        const float* sp = src + (size_t)(d0 + r) * DDIM + f0 + q * 16;
#pragma unroll
        for (int j = 0; j < 4; ++j) {
            float4 v = *(const float4*)(sp + j * 4);
            int c = q * 16 + j * 4;
            tileT[(c + 0) * 65 + r] = v.x;
            tileT[(c + 1) * 65 + r] = v.y;
            tileT[(c + 2) * 65 + r] = v.z;
            tileT[(c + 3) * 65 + r] = v.w;
        }
        __syncthreads();
        const int c2 = t >> 2, dq = (t & 3) * 16;
        u16x8 o0, o1;
#pragma unroll
        for (int i = 0; i < 8; ++i) o0[i] = f2bf(tileT[c2 * 65 + dq + i]);
#pragma unroll
        for (int i = 0; i < 8; ++i) o1[i] = f2bf(tileT[c2 * 65 + dq + 8 + i]);
        u16* dp = dst + (size_t)(f0 + c2) * DDIM + d0 + dq;
        *(u16x8*)dp = o0;
        *(u16x8*)(dp + 8) = o1;
    }
}

// ------- grouped expert GEMM, bf16 path (R13-exact best: 55.8us merged) -------
// merged=1: grid 8192, id -> e=id&7 (XCD), slot=(id>>3)&1, n=(id>>4)&7, m=id>>7;
//           slot0 writes out0, slot1 writes out1 (combined later). accum must be 0.
// merged=0: grid 4096, id -> e=id&7, n=(id>>3)&7, m=id>>6.
// LDS A/B tiles 128x64 u16 + tok/w/bias scalars (34304 B). BK=64, 16 K-steps.
// Staging via global_load_lds width=16: linear LDS dest, pre-swizzled source
// chunk^(row&7); ds_read applies same involution (row&7 == lm&7).
__global__ __launch_bounds__(256, 3) void moe_gemm_bf16(
    const u16* __restrict__ xb, const u16* __restrict__ WT,
    const float* __restrict__ bexp, const int* __restrict__ counts,
    const int* __restrict__ list_tok, const float* __restrict__ list_w,
    float* __restrict__ out0, float* __restrict__ out1,
    int merged, int grp_base, int accum) {
    const int id = blockIdx.x;
    int e, slot, n, m;
    if (merged) {
        e = id & 7; slot = (id >> 3) & 1; n = (id >> 4) & 7; m = id >> 7;
    } else {
        e = id & 7; slot = 0; n = (id >> 3) & 7; m = id >> 6;
    }
    const int grp = merged ? ((slot << 3) | e) : (grp_base + e);
    float* const out = (merged && slot) ? out1 : out0;
    int cnt = counts[grp];
    cnt = cnt < 0 ? 0 : (cnt > NTOK ? NTOK : cnt);
    const int m0 = m * 128;
    if (m0 >= cnt) return;
    const int n0 = n * 128;

    __shared__ __align__(16) u16 A_s[128 * 64]; // 16 KiB
    __shared__ __align__(16) u16 B_s[128 * 64]; // 16 KiB
    __shared__ int tok_s[128];
    __shared__ float w_s[128];
    __shared__ float bias_s[128];

    const int t = threadIdx.x;
    if (t < 128) {
        int r = m0 + t;
        int rr = r < cnt ? r : cnt - 1;
        tok_s[t] = list_tok[grp * NTOK + rr] & (NTOK - 1);
        w_s[t] = (r < cnt) ? list_w[grp * NTOK + rr] : 0.f;
        bias_s[t] = bexp[e * DDIM + n0 + t];
    }
    __syncthreads();

    const int wave = t >> 6, lane = t & 63;
    // staging: issue s covers rows s*32 + (t>>3), chunk t&7 (16B). Linear LDS
    // dest = s*4096B + wave*1024B + lane*16B; global source chunk pre-swizzled.
    const int sr = t >> 3, ch = t & 7;
    const u16* ag[4];
    const u16* bg[4];
#pragma unroll
    for (int s = 0; s < 4; ++s) {
        int row = s * 32 + sr;
        int cs = ((ch ^ (row & 7)) << 3);
        ag[s] = xb + (size_t)tok_s[row] * DDIM + cs;
        bg[s] = WT + ((size_t)e * DDIM + n0 + row) * DDIM + cs;
    }
    u16* const al = A_s + wave * 512; // wave-uniform LDS bases (u16 units)
    u16* const bl = B_s + wave * 512;

    const int wm = wave >> 1, wn = wave & 1;
    const int lm = lane & 15, kc = lane >> 4;

    floatx4 acc[4][4];
#pragma unroll
    for (int mi = 0; mi < 4; ++mi)
#pragma unroll
        for (int ni = 0; ni < 4; ++ni) acc[mi][ni] = (floatx4){0.f, 0.f, 0.f, 0.f};

    for (int kk = 0; kk < DDIM; kk += 64) {
        if (kk) __syncthreads();        // all waves done reading previous tile
#pragma unroll
        for (int s = 0; s < 4; ++s) {
            gl2l16(ag[s] + kk, al + s * 2048);
            gl2l16(bg[s] + kk, bl + s * 2048);
        }
        __syncthreads();                // drains vmcnt(0): tile resident
#pragma unroll
        for (int ks = 0; ks < 2; ++ks) {
            const int c = (((ks * 4 + kc) ^ (lm & 7)) << 3); // row&7 == lm&7
            bf16x8 af[4], bfr[4];
#pragma unroll
            for (int mi = 0; mi < 4; ++mi)
                af[mi] = *(const bf16x8*)&A_s[(wm * 64 + mi * 16 + lm) * 64 + c];
#pragma unroll
            for (int ni = 0; ni < 4; ++ni)
                bfr[ni] = *(const bf16x8*)&B_s[(wn * 64 + ni * 16 + lm) * 64 + c];
#pragma unroll
            for (int mi = 0; mi < 4; ++mi)
#pragma unroll
                for (int ni = 0; ni < 4; ++ni)
                    acc[mi][ni] = __builtin_amdgcn_mfma_f32_16x16x32_bf16(
                        af[mi], bfr[ni], acc[mi][ni], 0, 0, 0);
        }
    }

    // epilogue: C row = (lane>>4)*4+reg, col = lane&15 within each 16x16 tile
#pragma unroll
    for (int mi = 0; mi < 4; ++mi) {
        int rb = wm * 64 + mi * 16 + (lane >> 4) * 4;
#pragma unroll
        for (int reg = 0; reg < 4; ++reg) {
            int r = rb + reg;
            if (m0 + r < cnt) {
                size_t tok = (size_t)tok_s[r];
                float w = w_s[r];
                float* yrow = out + tok * DDIM + n0;
#pragma unroll
                for (int ni = 0; ni < 4; ++ni) {
                    int col = wn * 64 + ni * 16 + lm;
                    float v = w * (acc[mi][ni][reg] + bias_s[col]);
                    if (accum) v += yrow[col];
                    yrow[col] = v;
                }
            }
        }
    }
}

// ------- combine: out += out1 (merged-mode slot1 partials), float4 grid-stride -------
__global__ __launch_bounds__(256) void combine_add(const float* __restrict__ a,
                                                   float* __restrict__ o, int n4) {
    int stride = gridDim.x * 256;
    for (int i = blockIdx.x * 256 + threadIdx.x; i < n4; i += stride) {
        float4 va = ((const float4*)a)[i];
        float4 vo = ((float4*)o)[i];
        vo.x += va.x; vo.y += va.y; vo.z += va.z; vo.w += va.w;
        ((float4*)o)[i] = vo;
    }
}

// ------- fp32-A fallback GEMM (tiny workspace only): reg-staged -------
__global__ __launch_bounds__(256) void moe_gemm_f32(
    const float* __restrict__ xf, const u16* __restrict__ WT,
    const float* __restrict__ bexp, const int* __restrict__ counts,
    const int* __restrict__ list_tok, const float* __restrict__ list_w,
    float* __restrict__ out, int grp_base, int accum) {
    const int id = blockIdx.x;
    const int e = id & 7;
    const int n = (id >> 3) & 7;
    const int m = id >> 6;
    const int grp = grp_base + e;
    int cnt = counts[grp];
    cnt = cnt < 0 ? 0 : (cnt > NTOK ? NTOK : cnt);
    const int m0 = m * 128;
    if (m0 >= cnt) return;
    const int n0 = n * 128;

    __shared__ __align__(16) u16 A_s[128 * 64];
    __shared__ __align__(16) u16 B_s[128 * 64];
    __shared__ int tok_s[128];
    __shared__ float w_s[128];
    __shared__ float bias_s[128];

    const int t = threadIdx.x;
    if (t < 128) {
        int r = m0 + t;
        int rr = r < cnt ? r : cnt - 1;
        tok_s[t] = list_tok[grp * NTOK + rr] & (NTOK - 1);
        w_s[t] = (r < cnt) ? list_w[grp * NTOK + rr] : 0.f;
        bias_s[t] = bexp[e * DDIM + n0 + t];
    }
    __syncthreads();

    const int sr = t >> 3;
    const int ch = t & 7;
    const int co = ch * 8;

    size_t arow[4];
    u16 *adst[4], *bdst[4];
#pragma unroll
    for (int s = 0; s < 4; ++s) {
        int row = s * 32 + sr;
        arow[s] = (size_t)tok_s[row] * DDIM + co;
        int cs = ((ch ^ (row & 7)) << 3);
        adst[s] = A_s + row * 64 + cs;
        bdst[s] = B_s + row * 64 + cs;
    }
    const u16* bsrc = WT + ((size_t)e * DDIM + n0 + sr) * DDIM + co;

    const int lane = t & 63, wave = t >> 6;
    const int wm = wave >> 1, wn = wave & 1;
    const int lm = lane & 15, kc = lane >> 4;

    floatx4 acc[4][4];
#pragma unroll
    for (int mi = 0; mi < 4; ++mi)
#pragma unroll
        for (int ni = 0; ni < 4; ++ni) acc[mi][ni] = (floatx4){0.f, 0.f, 0.f, 0.f};

    u16x8 pb[4];
    float4 pfa[4][2];
#pragma unroll
    for (int s = 0; s < 4; ++s) {
        pfa[s][0] = *(const float4*)(xf + arow[s]);
        pfa[s][1] = *(const float4*)(xf + arow[s] + 4);
        pb[s] = *(const u16x8*)(bsrc + (size_t)s * 32 * DDIM);
    }

    for (int kk = 0; kk < DDIM; kk += 64) {
        u16x8 wa[4];
#pragma unroll
        for (int s = 0; s < 4; ++s) {
            wa[s][0] = f2bf(pfa[s][0].x); wa[s][1] = f2bf(pfa[s][0].y);
            wa[s][2] = f2bf(pfa[s][0].z); wa[s][3] = f2bf(pfa[s][0].w);
            wa[s][4] = f2bf(pfa[s][1].x); wa[s][5] = f2bf(pfa[s][1].y);
            wa[s][6] = f2bf(pfa[s][1].z); wa[s][7] = f2bf(pfa[s][1].w);
        }
        __syncthreads();
#pragma unroll
        for (int s = 0; s < 4; ++s) {
            *(u16x8*)adst[s] = wa[s];
            *(u16x8*)bdst[s] = pb[s];
        }
        __syncthreads();
        const int nk = kk + 64;
        if (nk < DDIM) {
#pragma unroll
            for (int s = 0; s < 4; ++s) {
                pfa[s][0] = *(const float4*)(xf + arow[s] + nk);
                pfa[s][1] = *(const float4*)(xf + arow[s] + nk + 4);
                pb[s] = *(const u16x8*)(bsrc + (size_t)s * 32 * DDIM + nk);
            }
        }
#pragma unroll
        for (int ks = 0; ks < 2; ++ks) {
            bf16x8 af[4], bfr[4];
#pragma unroll
            for (int mi = 0; mi < 4; ++mi) {
                int row = wm * 64 + mi * 16 + lm;
                int c = (((ks * 4 + kc) ^ (row & 7)) << 3);
                af[mi] = *(const bf16x8*)&A_s[row * 64 + c];
            }
#pragma unroll
            for (int ni = 0; ni < 4; ++ni) {
                int row = wn * 64 + ni * 16 + lm;
                int c = (((ks * 4 + kc) ^ (row & 7)) << 3);
                bfr[ni] = *(const bf16x8*)&B_s[row * 64 + c];
            }
#pragma unroll
            for (int mi = 0; mi < 4; ++mi)
#pragma unroll
                for (int ni = 0; ni < 4; ++ni)
                    acc[mi][ni] = __builtin_amdgcn_mfma_f32_16x16x32_bf16(
                        af[mi], bfr[ni], acc[mi][ni], 0, 0, 0);
        }
    }

#pragma unroll
    for (int mi = 0; mi < 4; ++mi) {
        int rb = wm * 64 + mi * 16 + (lane >> 4) * 4;
#pragma unroll
        for (int reg = 0; reg < 4; ++reg) {
            int r = rb + reg;
            if (m0 + r < cnt) {
                size_t tok = (size_t)tok_s[r];
                float w = w_s[r];
                float* yrow = out + tok * DDIM + n0;
#pragma unroll
                for (int ni = 0; ni < 4; ++ni) {
                    int col = wn * 64 + ni * 16 + lm;
                    float v = w * (acc[mi][ni][reg] + bias_s[col]);
                    if (accum) v += yrow[col];
                    yrow[col] = v;
                }
            }
        }
    }
}

extern "C" void kernel_launch(void* const* d_in, const int* in_sizes, int n_in,
                              void* d_out, int out_size, void* d_ws, size_t ws_size,
                              hipStream_t stream) {
    const float* x     = (const float*)d_in[0];
    const float* noise = (const float*)d_in[1];
    const float* Wr    = (const float*)d_in[2];
    const float* br    = (const float*)d_in[3];
    const float* gamma = (const float*)d_in[4];
    const float* beta  = (const float*)d_in[5];
    const float* Wexp  = (const float*)d_in[6];
    const float* bexp  = (const float*)d_in[7];
    float* out = (float*)d_out;

    unsigned char* ws = (unsigned char*)d_ws;
    u16* WT       = (u16*)ws;                               // 16 MiB
    int* counts   = (int*)(ws + 16777216);                  // 64 B (pad 256)
    int* list_tok = (int*)(ws + 16777472);                  // 512 KiB
    float* list_w = (float*)(ws + 17301760);                // 512 KiB
    u16* xb       = (u16*)(ws + 17924352);                  // 16 MiB
    float* out1   = (float*)(ws + 34701568);                // 32 MiB (merged mode)
    const size_t need_bf16   = 34701568;                    // ~33.1 MiB
    const size_t need_merged = 34701568 + 33554432;         // ~65.1 MiB

    const int have_bf16 = ws_size >= need_bf16;

    // zero the 16 group counters (graph-capturable), then fused aux launch:
    // routing w/ direct list append (blocks 0..2047) + W transpose (2048..4095)
    hipMemsetAsync(counts, 0, 16 * sizeof(int), stream);
    routing_and_transpose<<<4096, 256, 0, stream>>>(
        x, noise, Wr, br, gamma, beta, Wexp, counts, list_tok, list_w,
        xb, WT, have_bf16);

    if (ws_size >= need_merged) {
        moe_gemm_bf16<<<dim3(8192), 256, 0, stream>>>(
            xb, WT, bexp, counts, list_tok, list_w, out, out1, 1, 0, 0);
        combine_add<<<2048, 256, 0, stream>>>(out1, out, NTOK * DDIM / 4);
    } else if (have_bf16) {
        moe_gemm_bf16<<<dim3(4096), 256, 0, stream>>>(
            xb, WT, bexp, counts, list_tok, list_w, out, out, 0, 0, 0);
        moe_gemm_bf16<<<dim3(4096), 256, 0, stream>>>(
            xb, WT, bexp, counts, list_tok, list_w, out, out, 0, 8, 1);
    } else {
        moe_gemm_f32<<<dim3(4096), 256, 0, stream>>>(
            x, WT, bexp, counts, list_tok, list_w, out, 0, 0);
        moe_gemm_f32<<<dim3(4096), 256, 0, stream>>>(
            x, WT, bexp, counts, list_tok, list_w, out, 8, 1);
    }
}

// Round 16
// 209.442 us; speedup vs baseline: 1.7154x; 1.7154x over previous
//
#include <hip/hip_runtime.h>
#include <hip/hip_bf16.h>

// MoEProcessor: B=4,S=2048 -> T=8192 tokens, D=1024, E=8, K=2. fp32 in/out.
// Round 23: REVERT to session-best measured config (round-8/R15, 211.0us).
// R22 post-mortem: direct-append atomics = 16K contended RMWs on 16 addrs
// with return-value dependency -> ~1.1K serialized L2 round-trips ~200us
// (routing_and_transpose 203us, VALUBusy 4.4%). Guideline 12 violation;
// ballot-compaction build_lists WAS the aggregation. Restored.
// Config: fused routing+transpose (no atomics) -> build_lists (ballot)
// -> merged GEMM (34304B LDS, LDS scalars, BK=64, (256,4): best of 5
// measured GEMM variants at ~58us) -> combine_add.

typedef unsigned short u16;
typedef __bf16 bf16x8 __attribute__((ext_vector_type(8)));
typedef float floatx4 __attribute__((ext_vector_type(4)));
typedef unsigned short u16x8 __attribute__((ext_vector_type(8)));
typedef unsigned short u16x4 __attribute__((ext_vector_type(4)));

#define NTOK 8192
#define DDIM 1024
#define NEXP 8

__device__ __forceinline__ u16 f2bf(float f) {
    union { float f; unsigned int i; } c; c.f = f;
    unsigned int i = c.i;
    return (u16)((i + 0x7fffu + ((i >> 16) & 1u)) >> 16);
}

// async 16B-per-lane global->LDS copy. LDS dest is wave-uniform base + lane*16.
__device__ __forceinline__ void gl2l16(const u16* g, u16* l) {
    __builtin_amdgcn_global_load_lds(
        (const __attribute__((address_space(1))) unsigned int*)g,
        (__attribute__((address_space(3))) unsigned int*)l, 16, 0, 0);
}

// ---- fused aux: blocks 0..2047 = routing; blocks 2048..4095 = W transpose ----
__global__ __launch_bounds__(256) void routing_and_transpose(
    const float* __restrict__ x, const float* __restrict__ noise,
    const float* __restrict__ Wr, const float* __restrict__ br,
    const float* __restrict__ gamma, const float* __restrict__ beta,
    const float* __restrict__ W,
    int* __restrict__ e01, float2* __restrict__ w01,
    u16* __restrict__ xb, u16* __restrict__ WT, int wxb) {
    __shared__ __align__(16) float smem[NEXP * DDIM]; // 32 KiB union
    const int t = threadIdx.x;

    if (blockIdx.x < 2048) {
        // ---------------- routing role ----------------
        float (*wrT)[DDIM] = (float(*)[DDIM])smem;     // [8][1024]
#pragma unroll
        for (int i = 0; i < 8; ++i) {
            int f4 = i * 256 + t;
            int d = f4 >> 1, half = (f4 & 1) * 4;
            float4 v = *(const float4*)&Wr[d * 8 + half];
            wrT[half + 0][d] = v.x; wrT[half + 1][d] = v.y;
            wrT[half + 2][d] = v.z; wrT[half + 3][d] = v.w;
        }
        __syncthreads();

        const int wave = t >> 6, lane = t & 63;
        const int tok = blockIdx.x * 4 + wave;
        const float4* xrow = (const float4*)(x + (size_t)tok * DDIM);
        u16* xbrow = xb + (size_t)tok * DDIM;
        float acc[8];
#pragma unroll
        for (int e = 0; e < 8; ++e) acc[e] = 0.f;
#pragma unroll
        for (int i = 0; i < 4; ++i) {
            int d4 = i * 64 + lane;
            float4 xv = xrow[d4];
            if (wxb) {
                u16x4 b;
                b[0] = f2bf(xv.x); b[1] = f2bf(xv.y);
                b[2] = f2bf(xv.z); b[3] = f2bf(xv.w);
                *(u16x4*)(xbrow + d4 * 4) = b;
            }
#pragma unroll
            for (int e = 0; e < 8; ++e) {
                float4 wv = *(const float4*)&wrT[e][d4 * 4];
                acc[e] += xv.x * wv.x + xv.y * wv.y + xv.z * wv.z + xv.w * wv.w;
            }
        }
#pragma unroll
        for (int off = 32; off >= 1; off >>= 1) {
#pragma unroll
            for (int e = 0; e < 8; ++e) acc[e] += __shfl_xor(acc[e], off, 64);
        }
        if (lane == 0) {
            float lg[8], mu = 0.f;
#pragma unroll
            for (int e = 0; e < 8; ++e) { lg[e] = acc[e] + br[e]; mu += lg[e]; }
            mu *= 0.125f;
            float var = 0.f;
#pragma unroll
            for (int e = 0; e < 8; ++e) { float d = lg[e] - mu; var += d * d; }
            var *= 0.125f;
            float rstd = rsqrtf(var + 1e-5f);
            float ln[8], mx = -1e30f;
#pragma unroll
            for (int e = 0; e < 8; ++e) {
                ln[e] = (lg[e] - mu) * rstd * gamma[e] + beta[e];
                mx = fmaxf(mx, ln[e]);
            }
            float s = 0.f, p[8];
#pragma unroll
            for (int e = 0; e < 8; ++e) { p[e] = expf(ln[e] - mx); s += p[e]; }
            float inv = 1.f / s, r[8];
#pragma unroll
            for (int e = 0; e < 8; ++e)
                r[e] = p[e] * inv + noise[(size_t)tok * 8 + e];
            int i0 = 0; float v0 = r[0];
#pragma unroll
            for (int e = 1; e < 8; ++e) if (r[e] > v0) { v0 = r[e]; i0 = e; }
            int i1 = -1; float v1 = -1e30f;
#pragma unroll
            for (int e = 0; e < 8; ++e)
                if (e != i0 && r[e] > v1) { v1 = r[e]; i1 = e; }
            float w0 = 1.f / (1.f + expf(v1 - v0));
            e01[tok] = i0 | (i1 << 8);
            w01[tok] = make_float2(w0, 1.f - w0);
        }
    } else {
        // ---------------- transpose role ----------------
        float* tileT = smem;                           // 64*65 floats used
        const int id2 = blockIdx.x - 2048;             // 0..2047
        const int e = id2 >> 8, d0 = ((id2 >> 4) & 15) * 64, f0 = (id2 & 15) * 64;
        const float* src = W + (size_t)e * DDIM * DDIM;
        u16* dst = WT + (size_t)e * DDIM * DDIM;
        const int r = t >> 2, q = t & 3;
        const float* sp = src + (size_t)(d0 + r) * DDIM + f0 + q * 16;
#pragma unroll
        for (int j = 0; j < 4; ++j) {
            float4 v = *(const float4*)(sp + j * 4);
            int c = q * 16 + j * 4;
            tileT[(c + 0) * 65 + r] = v.x;
            tileT[(c + 1) * 65 + r] = v.y;
            tileT[(c + 2) * 65 + r] = v.z;
            tileT[(c + 3) * 65 + r] = v.w;
        }
        __syncthreads();
        const int c2 = t >> 2, dq = (t & 3) * 16;
        u16x8 o0, o1;
#pragma unroll
        for (int i = 0; i < 8; ++i) o0[i] = f2bf(tileT[c2 * 65 + dq + i]);
#pragma unroll
        for (int i = 0; i < 8; ++i) o1[i] = f2bf(tileT[c2 * 65 + dq + 8 + i]);
        u16* dp = dst + (size_t)(f0 + c2) * DDIM + d0 + dq;
        *(u16x8*)dp = o0;
        *(u16x8*)(dp + 8) = o1;
    }
}

// ---- build_lists: one block per (slot,expert) group, ballot-compaction ----
__global__ __launch_bounds__(256) void build_lists(
    const int* __restrict__ e01, const float2* __restrict__ w01,
    int* __restrict__ counts, int* __restrict__ list_tok, float* __restrict__ list_w) {
    const int g = blockIdx.x;            // 0..15: slot = g>>3, expert = g&7
    const int slot = g >> 3, ex = g & 7;
    const int t = threadIdx.x, wave = t >> 6, lane = t & 63;
    __shared__ int wtot[4];
    int base = 0;
    int packed = e01[t];
    for (int start = 0; start < NTOK; start += 256) {
        int nxt = (start + 256 < NTOK) ? e01[start + 256 + t] : 0;
        int tok = start + t;
        int e = slot ? ((packed >> 8) & 0xff) : (packed & 0xff);
        bool sel = (e == ex);
        unsigned long long m = __ballot(sel);
        int prefix = __popcll(m & ((1ULL << lane) - 1ULL));
        if (lane == 0) wtot[wave] = __popcll(m);
        __syncthreads();
        int wbase = 0;
#pragma unroll
        for (int wv = 0; wv < 4; ++wv) if (wv < wave) wbase += wtot[wv];
        int total = wtot[0] + wtot[1] + wtot[2] + wtot[3];
        if (sel) {
            float2 w2 = w01[tok];
            int pos = base + wbase + prefix;
            list_tok[g * NTOK + pos] = tok;
            list_w[g * NTOK + pos] = slot ? w2.y : w2.x;
        }
        base += total;
        __syncthreads();
        packed = nxt;
    }
    if (t == 0) counts[g] = base;
}

// ------- grouped expert GEMM, bf16 path: global_load_lds staging (m97 struct) -------
// merged=1: grid 8192, id -> e=id&7 (XCD), slot=(id>>3)&1, n=(id>>4)&7, m=id>>7;
//           slot0 writes out0, slot1 writes out1 (combined later). accum must be 0.
// merged=0: grid 4096, id -> e=id&7, n=(id>>3)&7, m=id>>6.
// LDS A/B tiles 128x64 u16 + tok/w/bias scalars (34304 B). BK=64, 16 K-steps.
// (256,4): 2 blocks/CU measured (64KB LDS granule); best GEMM variant (~58us).
__global__ __launch_bounds__(256, 4) void moe_gemm_bf16(
    const u16* __restrict__ xb, const u16* __restrict__ WT,
    const float* __restrict__ bexp, const int* __restrict__ counts,
    const int* __restrict__ list_tok, const float* __restrict__ list_w,
    float* __restrict__ out0, float* __restrict__ out1,
    int merged, int grp_base, int accum) {
    const int id = blockIdx.x;
    int e, slot, n, m;
    if (merged) {
        e = id & 7; slot = (id >> 3) & 1; n = (id >> 4) & 7; m = id >> 7;
    } else {
        e = id & 7; slot = 0; n = (id >> 3) & 7; m = id >> 6;
    }
    const int grp = merged ? ((slot << 3) | e) : (grp_base + e);
    float* const out = (merged && slot) ? out1 : out0;
    int cnt = counts[grp];
    cnt = cnt < 0 ? 0 : (cnt > NTOK ? NTOK : cnt);
    const int m0 = m * 128;
    if (m0 >= cnt) return;
    const int n0 = n * 128;

    __shared__ __align__(16) u16 A_s[128 * 64]; // 16 KiB
    __shared__ __align__(16) u16 B_s[128 * 64]; // 16 KiB
    __shared__ int tok_s[128];
    __shared__ float w_s[128];
    __shared__ float bias_s[128];

    const int t = threadIdx.x;
    if (t < 128) {
        int r = m0 + t;
        int rr = r < cnt ? r : cnt - 1;
        tok_s[t] = list_tok[grp * NTOK + rr] & (NTOK - 1);
        w_s[t] = (r < cnt) ? list_w[grp * NTOK + rr] : 0.f;
        bias_s[t] = bexp[e * DDIM + n0 + t];
    }
    __syncthreads();

    const int wave = t >> 6, lane = t & 63;
    // staging: issue s covers rows s*32 + (t>>3), chunk t&7 (16B). Linear LDS
    // dest = s*4096B + wave*1024B + lane*16B; global source chunk pre-swizzled.
    const int sr = t >> 3, ch = t & 7;
    const u16* ag[4];
    const u16* bg[4];
#pragma unroll
    for (int s = 0; s < 4; ++s) {
        int row = s * 32 + sr;
        int cs = ((ch ^ (row & 7)) << 3);
        ag[s] = xb + (size_t)tok_s[row] * DDIM + cs;
        bg[s] = WT + ((size_t)e * DDIM + n0 + row) * DDIM + cs;
    }
    u16* const al = A_s + wave * 512; // wave-uniform LDS bases (u16 units)
    u16* const bl = B_s + wave * 512;

    const int wm = wave >> 1, wn = wave & 1;
    const int lm = lane & 15, kc = lane >> 4;

    floatx4 acc[4][4];
#pragma unroll
    for (int mi = 0; mi < 4; ++mi)
#pragma unroll
        for (int ni = 0; ni < 4; ++ni) acc[mi][ni] = (floatx4){0.f, 0.f, 0.f, 0.f};

    for (int kk = 0; kk < DDIM; kk += 64) {
        if (kk) __syncthreads();        // all waves done reading previous tile
#pragma unroll
        for (int s = 0; s < 4; ++s) {
            gl2l16(ag[s] + kk, al + s * 2048);
            gl2l16(bg[s] + kk, bl + s * 2048);
        }
        __syncthreads();                // drains vmcnt(0): tile resident
#pragma unroll
        for (int ks = 0; ks < 2; ++ks) {
            const int c = (((ks * 4 + kc) ^ (lm & 7)) << 3); // row&7 == lm&7
            bf16x8 af[4], bfr[4];
#pragma unroll
            for (int mi = 0; mi < 4; ++mi)
                af[mi] = *(const bf16x8*)&A_s[(wm * 64 + mi * 16 + lm) * 64 + c];
#pragma unroll
            for (int ni = 0; ni < 4; ++ni)
                bfr[ni] = *(const bf16x8*)&B_s[(wn * 64 + ni * 16 + lm) * 64 + c];
#pragma unroll
            for (int mi = 0; mi < 4; ++mi)
#pragma unroll
                for (int ni = 0; ni < 4; ++ni)
                    acc[mi][ni] = __builtin_amdgcn_mfma_f32_16x16x32_bf16(
                        af[mi], bfr[ni], acc[mi][ni], 0, 0, 0);
        }
    }

    // epilogue: C row = (lane>>4)*4+reg, col = lane&15 within each 16x16 tile
#pragma unroll
    for (int mi = 0; mi < 4; ++mi) {
        int rb = wm * 64 + mi * 16 + (lane >> 4) * 4;
#pragma unroll
        for (int reg = 0; reg < 4; ++reg) {
            int r = rb + reg;
            if (m0 + r < cnt) {
                size_t tok = (size_t)tok_s[r];
                float w = w_s[r];
                float* yrow = out + tok * DDIM + n0;
#pragma unroll
                for (int ni = 0; ni < 4; ++ni) {
                    int col = wn * 64 + ni * 16 + lm;
                    float v = w * (acc[mi][ni][reg] + bias_s[col]);
                    if (accum) v += yrow[col];
                    yrow[col] = v;
                }
            }
        }
    }
}

// ------- combine: out += out1 (merged-mode slot1 partials), float4 grid-stride -------
__global__ __launch_bounds__(256) void combine_add(const float* __restrict__ a,
                                                   float* __restrict__ o, int n4) {
    int stride = gridDim.x * 256;
    for (int i = blockIdx.x * 256 + threadIdx.x; i < n4; i += stride) {
        float4 va = ((const float4*)a)[i];
        float4 vo = ((float4*)o)[i];
        vo.x += va.x; vo.y += va.y; vo.z += va.z; vo.w += va.w;
        ((float4*)o)[i] = vo;
    }
}

// ------- fp32-A fallback GEMM (tiny workspace only): reg-staged -------
__global__ __launch_bounds__(256) void moe_gemm_f32(
    const float* __restrict__ xf, const u16* __restrict__ WT,
    const float* __restrict__ bexp, const int* __restrict__ counts,
    const int* __restrict__ list_tok, const float* __restrict__ list_w,
    float* __restrict__ out, int grp_base, int accum) {
    const int id = blockIdx.x;
    const int e = id & 7;
    const int n = (id >> 3) & 7;
    const int m = id >> 6;
    const int grp = grp_base + e;
    int cnt = counts[grp];
    cnt = cnt < 0 ? 0 : (cnt > NTOK ? NTOK : cnt);
    const int m0 = m * 128;
    if (m0 >= cnt) return;
    const int n0 = n * 128;

    __shared__ __align__(16) u16 A_s[128 * 64];
    __shared__ __align__(16) u16 B_s[128 * 64];
    __shared__ int tok_s[128];
    __shared__ float w_s[128];
    __shared__ float bias_s[128];

    const int t = threadIdx.x;
    if (t < 128) {
        int r = m0 + t;
        int rr = r < cnt ? r : cnt - 1;
        tok_s[t] = list_tok[grp * NTOK + rr] & (NTOK - 1);
        w_s[t] = (r < cnt) ? list_w[grp * NTOK + rr] : 0.f;
        bias_s[t] = bexp[e * DDIM + n0 + t];
    }
    __syncthreads();

    const int sr = t >> 3;
    const int ch = t & 7;
    const int co = ch * 8;

    size_t arow[4];
    u16 *adst[4], *bdst[4];
#pragma unroll
    for (int s = 0; s < 4; ++s) {
        int row = s * 32 + sr;
        arow[s] = (size_t)tok_s[row] * DDIM + co;
        int cs = ((ch ^ (row & 7)) << 3);
        adst[s] = A_s + row * 64 + cs;
        bdst[s] = B_s + row * 64 + cs;
    }
    const u16* bsrc = WT + ((size_t)e * DDIM + n0 + sr) * DDIM + co;

    const int lane = t & 63, wave = t >> 6;
    const int wm = wave >> 1, wn = wave & 1;
    const int lm = lane & 15, kc = lane >> 4;

    floatx4 acc[4][4];
#pragma unroll
    for (int mi = 0; mi < 4; ++mi)
#pragma unroll
        for (int ni = 0; ni < 4; ++ni) acc[mi][ni] = (floatx4){0.f, 0.f, 0.f, 0.f};

    u16x8 pb[4];
    float4 pfa[4][2];
#pragma unroll
    for (int s = 0; s < 4; ++s) {
        pfa[s][0] = *(const float4*)(xf + arow[s]);
        pfa[s][1] = *(const float4*)(xf + arow[s] + 4);
        pb[s] = *(const u16x8*)(bsrc + (size_t)s * 32 * DDIM);
    }

    for (int kk = 0; kk < DDIM; kk += 64) {
        u16x8 wa[4];
#pragma unroll
        for (int s = 0; s < 4; ++s) {
            wa[s][0] = f2bf(pfa[s][0].x); wa[s][1] = f2bf(pfa[s][0].y);
            wa[s][2] = f2bf(pfa[s][0].z); wa[s][3] = f2bf(pfa[s][0].w);
            wa[s][4] = f2bf(pfa[s][1].x); wa[s][5] = f2bf(pfa[s][1].y);
            wa[s][6] = f2bf(pfa[s][1].z); wa[s][7] = f2bf(pfa[s][1].w);
        }
        __syncthreads();
#pragma unroll
        for (int s = 0; s < 4; ++s) {
            *(u16x8*)adst[s] = wa[s];
            *(u16x8*)bdst[s] = pb[s];
        }
        __syncthreads();
        const int nk = kk + 64;
        if (nk < DDIM) {
#pragma unroll
            for (int s = 0; s < 4; ++s) {
                pfa[s][0] = *(const float4*)(xf + arow[s] + nk);
                pfa[s][1] = *(const float4*)(xf + arow[s] + nk + 4);
                pb[s] = *(const u16x8*)(bsrc + (size_t)s * 32 * DDIM + nk);
            }
        }
#pragma unroll
        for (int ks = 0; ks < 2; ++ks) {
            bf16x8 af[4], bfr[4];
#pragma unroll
            for (int mi = 0; mi < 4; ++mi) {
                int row = wm * 64 + mi * 16 + lm;
                int c = (((ks * 4 + kc) ^ (row & 7)) << 3);
                af[mi] = *(const bf16x8*)&A_s[row * 64 + c];
            }
#pragma unroll
            for (int ni = 0; ni < 4; ++ni) {
                int row = wn * 64 + ni * 16 + lm;
                int c = (((ks * 4 + kc) ^ (row & 7)) << 3);
                bfr[ni] = *(const bf16x8*)&B_s[row * 64 + c];
            }
#pragma unroll
            for (int mi = 0; mi < 4; ++mi)
#pragma unroll
                for (int ni = 0; ni < 4; ++ni)
                    acc[mi][ni] = __builtin_amdgcn_mfma_f32_16x16x32_bf16(
                        af[mi], bfr[ni], acc[mi][ni], 0, 0, 0);
        }
    }

#pragma unroll
    for (int mi = 0; mi < 4; ++mi) {
        int rb = wm * 64 + mi * 16 + (lane >> 4) * 4;
#pragma unroll
        for (int reg = 0; reg < 4; ++reg) {
            int r = rb + reg;
            if (m0 + r < cnt) {
                size_t tok = (size_t)tok_s[r];
                float w = w_s[r];
                float* yrow = out + tok * DDIM + n0;
#pragma unroll
                for (int ni = 0; ni < 4; ++ni) {
                    int col = wn * 64 + ni * 16 + lm;
                    float v = w * (acc[mi][ni][reg] + bias_s[col]);
                    if (accum) v += yrow[col];
                    yrow[col] = v;
                }
            }
        }
    }
}

extern "C" void kernel_launch(void* const* d_in, const int* in_sizes, int n_in,
                              void* d_out, int out_size, void* d_ws, size_t ws_size,
                              hipStream_t stream) {
    const float* x     = (const float*)d_in[0];
    const float* noise = (const float*)d_in[1];
    const float* Wr    = (const float*)d_in[2];
    const float* br    = (const float*)d_in[3];
    const float* gamma = (const float*)d_in[4];
    const float* beta  = (const float*)d_in[5];
    const float* Wexp  = (const float*)d_in[6];
    const float* bexp  = (const float*)d_in[7];
    float* out = (float*)d_out;

    unsigned char* ws = (unsigned char*)d_ws;
    u16* WT       = (u16*)ws;                               // 16 MiB
    int* counts   = (int*)(ws + 16777216);                  // 64 B (pad 256)
    int* list_tok = (int*)(ws + 16777472);                  // 512 KiB
    float* list_w = (float*)(ws + 17301760);                // 512 KiB
    int* e01      = (int*)(ws + 17826048);                  // 32 KiB
    float2* w01   = (float2*)(ws + 17858816);               // 64 KiB
    u16* xb       = (u16*)(ws + 17924352);                  // 16 MiB
    float* out1   = (float*)(ws + 34701568);                // 32 MiB (merged mode)
    const size_t need_bf16   = 34701568;                    // ~33.1 MiB
    const size_t need_merged = 34701568 + 33554432;         // ~65.1 MiB

    const int have_bf16 = ws_size >= need_bf16;

    // fused aux launch: routing (blocks 0..2047) + W transpose (2048..4095)
    routing_and_transpose<<<4096, 256, 0, stream>>>(
        x, noise, Wr, br, gamma, beta, Wexp, e01, w01, xb, WT, have_bf16);
    build_lists<<<16, 256, 0, stream>>>(e01, w01, counts, list_tok, list_w);

    if (ws_size >= need_merged) {
        moe_gemm_bf16<<<dim3(8192), 256, 0, stream>>>(
            xb, WT, bexp, counts, list_tok, list_w, out, out1, 1, 0, 0);
        combine_add<<<2048, 256, 0, stream>>>(out1, out, NTOK * DDIM / 4);
    } else if (have_bf16) {
        moe_gemm_bf16<<<dim3(4096), 256, 0, stream>>>(
            xb, WT, bexp, counts, list_tok, list_w, out, out, 0, 0, 0);
        moe_gemm_bf16<<<dim3(4096), 256, 0, stream>>>(
            xb, WT, bexp, counts, list_tok, list_w, out, out, 0, 8, 1);
    } else {
        moe_gemm_f32<<<dim3(4096), 256, 0, stream>>>(
            x, WT, bexp, counts, list_tok, list_w, out, 0, 0);
        moe_gemm_f32<<<dim3(4096), 256, 0, stream>>>(
            x, WT, bexp, counts, list_tok, list_w, out, 8, 1);
    }
}